// Round 5
// baseline (389.220 us; speedup 1.0000x reference)
//
#include <hip/hip_runtime.h>
#include <stdint.h>

#define NB 2
#define NH 16
#define SEQ 4096
#define DD 64
#define NM 16           // 256-row query blocks per head
#define QB 256
#define CH 256          // keys per chunk

typedef __attribute__((ext_vector_type(8)))  __bf16 bf16x8;
typedef __attribute__((ext_vector_type(16))) float  f32x16;
typedef __attribute__((ext_vector_type(2)))  unsigned int u32x2;

static __device__ __forceinline__ f32x16 zero16() {
    f32x16 z;
#pragma unroll
    for (int i = 0; i < 16; i++) z[i] = 0.0f;
    return z;
}

__global__ void __launch_bounds__(512, 4)
swa_kernel(const float* __restrict__ Q, const float* __restrict__ K,
           const float* __restrict__ V, const float* __restrict__ scale_p,
           float* __restrict__ out)
{
    // XCD-aware swizzle: 512 blocks, 512 % 8 == 0 -> simple bijective remap.
    int lid = (int)blockIdx.x;
    lid = (lid & 7) * 64 + (lid >> 3);
    const int m  = lid & 15;        // query block
    const int bh = lid >> 4;        // b*NH + h

    const float scale = scale_p[0];     // = 0.125 exactly (pow2) -> folding into Q is exact
    const float* Qb = Q + (size_t)bh * SEQ * DD;
    const float* Kb = K + (size_t)bh * SEQ * DD;
    const float* Vb = V + (size_t)bh * SEQ * DD;
    float*       Ob = out + (size_t)bh * SEQ * DD;

    const int tid  = threadIdx.x;
    const int lane = tid & 63;
    const int w    = tid >> 6;      // wave 0..7
    const int l31  = lane & 31;
    const int h5   = lane >> 5;

    // K chunk in fragment-major order: kl[kt(8)][s(4)][lane(64)][8 bf16] = 32 KB.
    // Inner-loop read = ds_read_b128 at lane*16 -> conflict-free.
    __shared__ __align__(16) unsigned char kl[32768];
    // V^T chunk [d=64][key=256] bf16, XOR-swizzled: byte ^= (row&15)<<4 -> 2-way max.
    __shared__ __align__(16) unsigned char vl[32768];

    // ---- Q fragments (B operand of swapped QK^T), prescaled by `scale`:
    // lane holds (Q*scale)[q=l31][16s + 8*h5 + e]
    bf16x8 qf[4];
    {
        const float* qp = Qb + (size_t)(m * QB + w * 32 + l31) * DD + 8 * h5;
#pragma unroll
        for (int s = 0; s < 4; s++) {
            float4 a = *(const float4*)(qp + 16 * s);
            float4 b = *(const float4*)(qp + 16 * s + 4);
            bf16x8 f;
            f[0] = (__bf16)(a.x * scale); f[1] = (__bf16)(a.y * scale);
            f[2] = (__bf16)(a.z * scale); f[3] = (__bf16)(a.w * scale);
            f[4] = (__bf16)(b.x * scale); f[5] = (__bf16)(b.y * scale);
            f[6] = (__bf16)(b.z * scale); f[7] = (__bf16)(b.w * scale);
            qf[s] = f;
        }
    }

    f32x16 accA0 = zero16(), accA1 = zero16();   // window A numerator (cols 0-31 / 32-63)
    f32x16 accB0 = zero16(), accB1 = zero16();   // window B numerator
    float dA = 0.0f, dB = 0.0f;                  // per-lane denominator partials

    for (int ci = 0; ci < 3; ci++) {
        const int ck = (m - 1 + ci) * CH;
        if (ck < 0 || ck >= SEQ) continue;       // m is block-uniform -> barrier-safe
        const bool inA = (m > 0) && (ci <= 1);   // window A = chunks 0,1
        const bool inB = (ci >= 1);              // window B = chunks 1,2 (m=15: chunk 1 only)

        __syncthreads();
        // ---- stage K chunk -> LDS (fragment-major bf16), one cvt per element total
        {
            const int key = tid >> 1, half = tid & 1;
            const float* kp = Kb + (size_t)(ck + key) * DD + 32 * half;
            float fl[32];
#pragma unroll
            for (int i = 0; i < 8; i++) {
                float4 t = *(const float4*)(kp + 4 * i);
                fl[4 * i] = t.x; fl[4 * i + 1] = t.y; fl[4 * i + 2] = t.z; fl[4 * i + 3] = t.w;
            }
#pragma unroll
            for (int g = 0; g < 4; g++) {
                const int sp = g >> 1, hg = g & 1;
                const int s = 2 * half + sp;
                bf16x8 o;
#pragma unroll
                for (int e = 0; e < 8; e++) o[e] = (__bf16)fl[16 * sp + 8 * hg + e];
                *(bf16x8*)(kl + ((key >> 5) * 4 + s) * 1024 + ((key & 31) + 32 * hg) * 16) = o;
            }
        }
        // ---- stage V^T chunk -> LDS bf16 (transpose + XOR swizzle)
        {
            const int kk = (tid & 127) * 2;      // key pair
            const int dg = tid >> 7;             // d block of 16
            const float* vp0 = Vb + (size_t)(ck + kk) * DD + dg * 16;
            const float* vp1 = vp0 + DD;
#pragma unroll
            for (int j = 0; j < 16; j += 4) {
                float4 a = *(const float4*)(vp0 + j);
                float4 b = *(const float4*)(vp1 + j);
                float av[4] = {a.x, a.y, a.z, a.w};
                float bv[4] = {b.x, b.y, b.z, b.w};
#pragma unroll
                for (int e = 0; e < 4; e++) {
                    union { __bf16 h[2]; uint32_t u; } pk;
                    pk.h[0] = (__bf16)av[e];
                    pk.h[1] = (__bf16)bv[e];
                    const int row = dg * 16 + j + e;
                    *(uint32_t*)(vl + ((row * 512 + kk * 2) ^ ((row & 15) << 4))) = pk.u;
                }
            }
        }
        __syncthreads();

        // ---- 8 key tiles of 32
        for (int kt = 0; kt < 8; kt++) {
            // K fragment from LDS (A operand): conflict-free ds_read_b128
            const unsigned char* kfb = kl + kt * 4096 + lane * 16;
            f32x16 st = zero16();
#pragma unroll
            for (int s = 0; s < 4; s++) {
                bf16x8 kf = *(const bf16x8*)(kfb + s * 1024);
                st = __builtin_amdgcn_mfma_f32_32x32x16_bf16(kf, qf[s], st, 0, 0, 0);
            }
            // st = S^T tile (already scaled): col(lane&31)=q, row=(r&3)+8*(r>>2)+4*h5 = key

            // ---- sigmoid, bf16 round, per-lane denominator (pre-round f32 sum)
            uint32_t wv[8];
            float dsum = 0.0f;
#pragma unroll
            for (int i = 0; i < 8; i++) {
                float p0 = __builtin_amdgcn_rcpf(1.0f + __expf(-st[2 * i]));
                float p1 = __builtin_amdgcn_rcpf(1.0f + __expf(-st[2 * i + 1]));
                dsum += p0 + p1;
                union { __bf16 h[2]; uint32_t u; } pk;
                pk.h[0] = (__bf16)p0;
                pk.h[1] = (__bf16)p1;
                wv[i] = pk.u;
            }
            if (inA) dA += dsum;
            if (inB) dB += dsum;

            // ---- P relayout: C-layout -> A-fragments via permlane32_swap
            // swap(x,y): ret[0] = {x.lo | y.lo}, ret[1] = {x.hi | y.hi}
            u32x2 rA = __builtin_amdgcn_permlane32_swap(wv[0], wv[2], false, false);
            u32x2 rB = __builtin_amdgcn_permlane32_swap(wv[1], wv[3], false, false);
            u32x2 rC = __builtin_amdgcn_permlane32_swap(wv[4], wv[6], false, false);
            u32x2 rD = __builtin_amdgcn_permlane32_swap(wv[5], wv[7], false, false);
            union { uint32_t u[4]; bf16x8 v; } A0, A1;
            A0.u[0] = rA[0]; A0.u[1] = rB[0]; A0.u[2] = rA[1]; A0.u[3] = rB[1]; // keys 8h5+{0..7}
            A1.u[0] = rC[0]; A1.u[1] = rD[0]; A1.u[2] = rC[1]; A1.u[3] = rD[1]; // keys 16+8h5+{0..7}

            // ---- V fragments from LDS (B operand), XOR-swizzled (2-way max)
            const int ko = kt * 64 + h5 * 16;
            const int x0 = (l31 & 15) << 4;
            bf16x8 v00 = *(const bf16x8*)(vl + ((l31 * 512 + ko) ^ x0));
            bf16x8 v01 = *(const bf16x8*)(vl + ((l31 * 512 + ko + 32) ^ x0));
            bf16x8 v10 = *(const bf16x8*)(vl + (((32 + l31) * 512 + ko) ^ x0));
            bf16x8 v11 = *(const bf16x8*)(vl + (((32 + l31) * 512 + ko + 32) ^ x0));

            if (inA) {
                accA0 = __builtin_amdgcn_mfma_f32_32x32x16_bf16(A0.v, v00, accA0, 0, 0, 0);
                accA0 = __builtin_amdgcn_mfma_f32_32x32x16_bf16(A1.v, v01, accA0, 0, 0, 0);
                accA1 = __builtin_amdgcn_mfma_f32_32x32x16_bf16(A0.v, v10, accA1, 0, 0, 0);
                accA1 = __builtin_amdgcn_mfma_f32_32x32x16_bf16(A1.v, v11, accA1, 0, 0, 0);
            }
            if (inB) {
                accB0 = __builtin_amdgcn_mfma_f32_32x32x16_bf16(A0.v, v00, accB0, 0, 0, 0);
                accB0 = __builtin_amdgcn_mfma_f32_32x32x16_bf16(A1.v, v01, accB0, 0, 0, 0);
                accB1 = __builtin_amdgcn_mfma_f32_32x32x16_bf16(A0.v, v10, accB1, 0, 0, 0);
                accB1 = __builtin_amdgcn_mfma_f32_32x32x16_bf16(A1.v, v11, accB1, 0, 0, 0);
            }
        }
    }

    // ---- epilogue: combine denominators, normalize, blend, store
    const float dAt = dA + __shfl_xor(dA, 32, 64);   // lane l: denom_A[query l&31]
    const float dBt = dB + __shfl_xor(dB, 32, 64);
    const float invA = __builtin_amdgcn_rcpf(dAt);
    const float invB = __builtin_amdgcn_rcpf(dBt);

#pragma unroll
    for (int r = 0; r < 16; r++) {
        const int cr = (r & 3) + 8 * (r >> 2) + 4 * h5;   // query row in wave tile
        const int j  = w * 32 + cr;                       // row within the 256-block
        const float ia = __shfl(invA, cr, 64);
        const float ib = __shfl(invB, cr, 64);
        float o0, o1;
        if (m == 0) {
            o0 = accB0[r] * ib;
            o1 = accB1[r] * ib;
        } else {
            const float alpha = (float)j * (1.0f / 255.0f);
            const float a0 = accA0[r] * ia, b0 = accB0[r] * ib;
            const float a1 = accA1[r] * ia, b1 = accB1[r] * ib;
            o0 = (1.0f - alpha) * a0 + alpha * b0;
            o1 = (1.0f - alpha) * a1 + alpha * b1;
        }
        float* orow = Ob + (size_t)(m * QB + j) * DD;
        orow[l31]      = o0;
        orow[32 + l31] = o1;
    }
}

extern "C" void kernel_launch(void* const* d_in, const int* in_sizes, int n_in,
                              void* d_out, int out_size, void* d_ws, size_t ws_size,
                              hipStream_t stream) {
    const float* Q = (const float*)d_in[0];
    const float* K = (const float*)d_in[1];
    const float* V = (const float*)d_in[2];
    const float* s = (const float*)d_in[3];
    float* out = (float*)d_out;
    dim3 grid(NB * NH * NM, 1, 1);   // 512
    dim3 block(512, 1, 1);
    hipLaunchKernelGGL(swa_kernel, grid, block, 0, stream, Q, K, V, s, out);
}

// Round 6
// 242.729 us; speedup vs baseline: 1.6035x; 1.6035x over previous
//
#include <hip/hip_runtime.h>
#include <stdint.h>

#define NB 2
#define NH 16
#define SEQ 4096
#define DD 64
#define NM 16           // 256-row query blocks per head
#define QB 256
#define CH 256          // keys per chunk

typedef __attribute__((ext_vector_type(8)))  __bf16 bf16x8;
typedef __attribute__((ext_vector_type(16))) float  f32x16;
typedef __attribute__((ext_vector_type(2)))  unsigned int u32x2;

static __device__ __forceinline__ f32x16 zero16() {
    f32x16 z;
#pragma unroll
    for (int i = 0; i < 16; i++) z[i] = 0.0f;
    return z;
}

// NOTE: 2nd launch_bounds arg: round-5 evidence shows hipcc treats it as
// min-BLOCKS/CU for this config ((512,4) -> VGPR capped at 64 -> accumulator
// spills -> 838 MB scratch traffic, 305us). (512,2) gave VGPR=128, no spill.
__global__ void __launch_bounds__(512, 2)
swa_kernel(const float* __restrict__ Q, const float* __restrict__ K,
           const float* __restrict__ V, const float* __restrict__ scale_p,
           float* __restrict__ out)
{
    // XCD-aware swizzle: 512 blocks, 512 % 8 == 0 -> simple bijective remap.
    int lid = (int)blockIdx.x;
    lid = (lid & 7) * 64 + (lid >> 3);
    const int m  = lid & 15;        // query block
    const int bh = lid >> 4;        // b*NH + h

    const float scale = scale_p[0];     // = 0.125 exactly (pow2) -> folding into Q is exact
    const float* Qb = Q + (size_t)bh * SEQ * DD;
    const float* Kb = K + (size_t)bh * SEQ * DD;
    const float* Vb = V + (size_t)bh * SEQ * DD;
    float*       Ob = out + (size_t)bh * SEQ * DD;

    const int tid  = threadIdx.x;
    const int lane = tid & 63;
    const int w    = tid >> 6;      // wave 0..7
    const int l31  = lane & 31;
    const int h5   = lane >> 5;

    // K chunk in fragment-major order: kl[kt(8)][s(4)][lane(64)][8 bf16] = 32 KB.
    // Inner-loop read = ds_read_b128 at lane*16 -> conflict-free.
    __shared__ __align__(16) unsigned char kl[32768];
    // V^T chunk [d=64][key=256] bf16, XOR-swizzled: byte ^= (row&15)<<4 -> 2-way max.
    __shared__ __align__(16) unsigned char vl[32768];

    // ---- Q fragments (B operand of swapped QK^T), prescaled by `scale`:
    // lane holds (Q*scale)[q=l31][16s + 8*h5 + e]
    bf16x8 qf[4];
    {
        const float* qp = Qb + (size_t)(m * QB + w * 32 + l31) * DD + 8 * h5;
#pragma unroll
        for (int s = 0; s < 4; s++) {
            float4 a = *(const float4*)(qp + 16 * s);
            float4 b = *(const float4*)(qp + 16 * s + 4);
            bf16x8 f;
            f[0] = (__bf16)(a.x * scale); f[1] = (__bf16)(a.y * scale);
            f[2] = (__bf16)(a.z * scale); f[3] = (__bf16)(a.w * scale);
            f[4] = (__bf16)(b.x * scale); f[5] = (__bf16)(b.y * scale);
            f[6] = (__bf16)(b.z * scale); f[7] = (__bf16)(b.w * scale);
            qf[s] = f;
        }
    }

    f32x16 accA0 = zero16(), accA1 = zero16();   // window A numerator (cols 0-31 / 32-63)
    f32x16 accB0 = zero16(), accB1 = zero16();   // window B numerator
    float dA = 0.0f, dB = 0.0f;                  // per-lane denominator partials

    for (int ci = 0; ci < 3; ci++) {
        const int ck = (m - 1 + ci) * CH;
        if (ck < 0 || ck >= SEQ) continue;       // m is block-uniform -> barrier-safe
        const bool inA = (m > 0) && (ci <= 1);   // window A = chunks 0,1
        const bool inB = (ci >= 1);              // window B = chunks 1,2 (m=15: chunk 1 only)

        __syncthreads();
        // ---- stage K chunk -> LDS (fragment-major bf16), one cvt per element total
        {
            const int key = tid >> 1, half = tid & 1;
            const float* kp = Kb + (size_t)(ck + key) * DD + 32 * half;
            float fl[32];
#pragma unroll
            for (int i = 0; i < 8; i++) {
                float4 t = *(const float4*)(kp + 4 * i);
                fl[4 * i] = t.x; fl[4 * i + 1] = t.y; fl[4 * i + 2] = t.z; fl[4 * i + 3] = t.w;
            }
#pragma unroll
            for (int g = 0; g < 4; g++) {
                const int sp = g >> 1, hg = g & 1;
                const int s = 2 * half + sp;
                bf16x8 o;
#pragma unroll
                for (int e = 0; e < 8; e++) o[e] = (__bf16)fl[16 * sp + 8 * hg + e];
                *(bf16x8*)(kl + ((key >> 5) * 4 + s) * 1024 + ((key & 31) + 32 * hg) * 16) = o;
            }
        }
        // ---- stage V^T chunk -> LDS bf16 (transpose + XOR swizzle)
        {
            const int kk = (tid & 127) * 2;      // key pair
            const int dg = tid >> 7;             // d block of 16
            const float* vp0 = Vb + (size_t)(ck + kk) * DD + dg * 16;
            const float* vp1 = vp0 + DD;
#pragma unroll
            for (int j = 0; j < 16; j += 4) {
                float4 a = *(const float4*)(vp0 + j);
                float4 b = *(const float4*)(vp1 + j);
                float av[4] = {a.x, a.y, a.z, a.w};
                float bv[4] = {b.x, b.y, b.z, b.w};
#pragma unroll
                for (int e = 0; e < 4; e++) {
                    union { __bf16 h[2]; uint32_t u; } pk;
                    pk.h[0] = (__bf16)av[e];
                    pk.h[1] = (__bf16)bv[e];
                    const int row = dg * 16 + j + e;
                    *(uint32_t*)(vl + ((row * 512 + kk * 2) ^ ((row & 15) << 4))) = pk.u;
                }
            }
        }
        __syncthreads();

        // ---- 8 key tiles of 32
        for (int kt = 0; kt < 8; kt++) {
            // K fragment from LDS (A operand): conflict-free ds_read_b128
            const unsigned char* kfb = kl + kt * 4096 + lane * 16;
            f32x16 st = zero16();
#pragma unroll
            for (int s = 0; s < 4; s++) {
                bf16x8 kf = *(const bf16x8*)(kfb + s * 1024);
                st = __builtin_amdgcn_mfma_f32_32x32x16_bf16(kf, qf[s], st, 0, 0, 0);
            }
            // st = S^T tile (already scaled): col(lane&31)=q, row=(r&3)+8*(r>>2)+4*h5 = key

            // ---- sigmoid, bf16 round, per-lane denominator (pre-round f32 sum)
            uint32_t wv[8];
            float dsum = 0.0f;
#pragma unroll
            for (int i = 0; i < 8; i++) {
                float p0 = __builtin_amdgcn_rcpf(1.0f + __expf(-st[2 * i]));
                float p1 = __builtin_amdgcn_rcpf(1.0f + __expf(-st[2 * i + 1]));
                dsum += p0 + p1;
                union { __bf16 h[2]; uint32_t u; } pk;
                pk.h[0] = (__bf16)p0;
                pk.h[1] = (__bf16)p1;
                wv[i] = pk.u;
            }
            if (inA) dA += dsum;
            if (inB) dB += dsum;

            // ---- P relayout: C-layout -> A-fragments via permlane32_swap
            // swap(x,y): ret[0] = {x.lo | y.lo}, ret[1] = {x.hi | y.hi}
            u32x2 rA = __builtin_amdgcn_permlane32_swap(wv[0], wv[2], false, false);
            u32x2 rB = __builtin_amdgcn_permlane32_swap(wv[1], wv[3], false, false);
            u32x2 rC = __builtin_amdgcn_permlane32_swap(wv[4], wv[6], false, false);
            u32x2 rD = __builtin_amdgcn_permlane32_swap(wv[5], wv[7], false, false);
            union { uint32_t u[4]; bf16x8 v; } A0, A1;
            A0.u[0] = rA[0]; A0.u[1] = rB[0]; A0.u[2] = rA[1]; A0.u[3] = rB[1]; // keys 8h5+{0..7}
            A1.u[0] = rC[0]; A1.u[1] = rD[0]; A1.u[2] = rC[1]; A1.u[3] = rD[1]; // keys 16+8h5+{0..7}

            // ---- V fragments from LDS (B operand), XOR-swizzled (2-way max)
            const int ko = kt * 64 + h5 * 16;
            const int x0 = (l31 & 15) << 4;
            bf16x8 v00 = *(const bf16x8*)(vl + ((l31 * 512 + ko) ^ x0));
            bf16x8 v01 = *(const bf16x8*)(vl + ((l31 * 512 + ko + 32) ^ x0));
            bf16x8 v10 = *(const bf16x8*)(vl + (((32 + l31) * 512 + ko) ^ x0));
            bf16x8 v11 = *(const bf16x8*)(vl + (((32 + l31) * 512 + ko + 32) ^ x0));

            if (inA) {
                accA0 = __builtin_amdgcn_mfma_f32_32x32x16_bf16(A0.v, v00, accA0, 0, 0, 0);
                accA0 = __builtin_amdgcn_mfma_f32_32x32x16_bf16(A1.v, v01, accA0, 0, 0, 0);
                accA1 = __builtin_amdgcn_mfma_f32_32x32x16_bf16(A0.v, v10, accA1, 0, 0, 0);
                accA1 = __builtin_amdgcn_mfma_f32_32x32x16_bf16(A1.v, v11, accA1, 0, 0, 0);
            }
            if (inB) {
                accB0 = __builtin_amdgcn_mfma_f32_32x32x16_bf16(A0.v, v00, accB0, 0, 0, 0);
                accB0 = __builtin_amdgcn_mfma_f32_32x32x16_bf16(A1.v, v01, accB0, 0, 0, 0);
                accB1 = __builtin_amdgcn_mfma_f32_32x32x16_bf16(A0.v, v10, accB1, 0, 0, 0);
                accB1 = __builtin_amdgcn_mfma_f32_32x32x16_bf16(A1.v, v11, accB1, 0, 0, 0);
            }
        }
    }

    // ---- epilogue: combine denominators, normalize, blend, store
    const float dAt = dA + __shfl_xor(dA, 32, 64);   // lane l: denom_A[query l&31]
    const float dBt = dB + __shfl_xor(dB, 32, 64);
    const float invA = __builtin_amdgcn_rcpf(dAt);
    const float invB = __builtin_amdgcn_rcpf(dBt);

#pragma unroll
    for (int r = 0; r < 16; r++) {
        const int cr = (r & 3) + 8 * (r >> 2) + 4 * h5;   // query row in wave tile
        const int j  = w * 32 + cr;                       // row within the 256-block
        const float ia = __shfl(invA, cr, 64);
        const float ib = __shfl(invB, cr, 64);
        float o0, o1;
        if (m == 0) {
            o0 = accB0[r] * ib;
            o1 = accB1[r] * ib;
        } else {
            const float alpha = (float)j * (1.0f / 255.0f);
            const float a0 = accA0[r] * ia, b0 = accB0[r] * ib;
            const float a1 = accA1[r] * ia, b1 = accB1[r] * ib;
            o0 = (1.0f - alpha) * a0 + alpha * b0;
            o1 = (1.0f - alpha) * a1 + alpha * b1;
        }
        float* orow = Ob + (size_t)(m * QB + j) * DD;
        orow[l31]      = o0;
        orow[32 + l31] = o1;
    }
}

extern "C" void kernel_launch(void* const* d_in, const int* in_sizes, int n_in,
                              void* d_out, int out_size, void* d_ws, size_t ws_size,
                              hipStream_t stream) {
    const float* Q = (const float*)d_in[0];
    const float* K = (const float*)d_in[1];
    const float* V = (const float*)d_in[2];
    const float* s = (const float*)d_in[3];
    float* out = (float*)d_out;
    dim3 grid(NB * NH * NM, 1, 1);   // 512
    dim3 block(512, 1, 1);
    hipLaunchKernelGGL(swa_kernel, grid, block, 0, stream, Q, K, V, s, out);
}